// Round 16
// baseline (205.552 us; speedup 1.0000x reference)
//
#include <hip/hip_runtime.h>
#include <hip/hip_bf16.h>
#include <stdint.h>

// Pipeline: out = (A @ x) @ Wc + cvec, where Wcs = Wo@Wv (bf16, row-major [o][i]),
// A = causal softmax(-cdist(pos)/8) (head-independent, rows sum to 1),
// cvec = Wo@bv + bo. B=2, S=2048, D=1024.
// R16 = R15 + axwc/out fused into one launch with ticket-based work assignment and
// per-tile producer->consumer gating (agent-scope acq/rel, R8-verified primitives).

typedef __attribute__((ext_vector_type(8))) short bf16x8;
typedef __attribute__((ext_vector_type(4))) float f32x4;
typedef __attribute__((ext_vector_type(4))) unsigned short us4;

#define AS1(p) (const __attribute__((address_space(1))) unsigned int*)(p)
#define AS3(p) (__attribute__((address_space(3))) unsigned int*)(p)

__device__ __forceinline__ unsigned short f2bf(float f) {
  union { float f; unsigned u; } v; v.f = f;
  unsigned r = v.u + 0x7FFFu + ((v.u >> 16) & 1u);   // RNE
  return (unsigned short)(r >> 16);
}

// ---------- k_pos: pos = x @ w3d.T + b3d ----------
__global__ void k_pos(const float* __restrict__ x, const float* __restrict__ w3d,
                      const float* __restrict__ b3d, float* __restrict__ pos) {
  __shared__ float red[12];
  const int row = blockIdx.x, t = threadIdx.x;
  const float4 xv = ((const float4*)(x + (size_t)row * 1024))[t];
  const float4 w0 = ((const float4*)(w3d))[t];
  const float4 w1 = ((const float4*)(w3d + 1024))[t];
  const float4 w2 = ((const float4*)(w3d + 2048))[t];
  float a0 = xv.x*w0.x + xv.y*w0.y + xv.z*w0.z + xv.w*w0.w;
  float a1 = xv.x*w1.x + xv.y*w1.y + xv.z*w1.z + xv.w*w1.w;
  float a2 = xv.x*w2.x + xv.y*w2.y + xv.z*w2.z + xv.w*w2.w;
  #pragma unroll
  for (int off = 32; off; off >>= 1) {
    a0 += __shfl_down(a0, off, 64);
    a1 += __shfl_down(a1, off, 64);
    a2 += __shfl_down(a2, off, 64);
  }
  if ((t & 63) == 0) { red[(t >> 6)*3] = a0; red[(t >> 6)*3 + 1] = a1; red[(t >> 6)*3 + 2] = a2; }
  __syncthreads();
  if (t == 0) {
    pos[(size_t)row*3 + 0] = red[0] + red[3] + red[6] + red[9]  + b3d[0];
    pos[(size_t)row*3 + 1] = red[1] + red[4] + red[7] + red[10] + b3d[1];
    pos[(size_t)row*3 + 2] = red[2] + red[5] + red[8] + red[11] + b3d[2];
  }
}

// ---------- k_fused: [0,1024) xT; [1024,2048) wvT; [2048,3072) wob+cvec;
//            [3072,7168) attn rows (needs only pos) ----------
__global__ void k_fused(const float* __restrict__ x, const float* __restrict__ wv,
                        const float* __restrict__ wo, const float* __restrict__ bv,
                        const float* __restrict__ bo, const float* __restrict__ pos,
                        unsigned short* __restrict__ xT, unsigned short* __restrict__ wvT,
                        unsigned short* __restrict__ wob, float* __restrict__ cvec,
                        unsigned short* __restrict__ Ab) {
  __shared__ __align__(16) float lsm[64 * 68];
  const int bx = blockIdx.x, t = threadIdx.x;
  if (bx < 1024) {
    const int b = bx >> 9, rest = bx & 511, st = rest >> 4, dt = rest & 15;
    const int s0 = st * 64, d0 = dt * 64;
    const int r = t >> 2, c4 = t & 3;
    const float* src = x + (size_t)(b * 2048 + s0 + r) * 1024 + d0;
    float (*ld)[68] = (float(*)[68])lsm;
    #pragma unroll
    for (int p = 0; p < 4; p++)
      *(float4*)&ld[r][(c4 + 4 * p) * 4] = ((const float4*)src)[c4 + 4 * p];
    __syncthreads();
    #pragma unroll
    for (int p = 0; p < 4; p++) {
      const int dl = (t >> 4) + (p << 4);
      us4 o;
      #pragma unroll
      for (int k = 0; k < 4; k++)
        ((unsigned short*)&o)[k] = f2bf(ld[(t & 15) * 4 + k][dl]);
      *(us4*)(xT + ((size_t)b << 21) + (size_t)(d0 + dl) * 2048 + s0 + (t & 15) * 4) = o;
    }
  } else if (bx < 2048) {
    const int bb = bx - 1024, tr = bb >> 5, tc = bb & 31;
    const int r = t >> 5, c = t & 31;
    float (*ld)[33] = (float(*)[33])lsm;
    #pragma unroll
    for (int rr = r; rr < 32; rr += 8)
      ld[rr][c] = wv[(size_t)(tr * 32 + rr) * 1024 + tc * 32 + c];
    __syncthreads();
    #pragma unroll
    for (int rr = r; rr < 32; rr += 8)
      wvT[(size_t)(tc * 32 + rr) * 1024 + tr * 32 + c] = f2bf(ld[c][rr]);
  } else if (bx < 3072) {
    const int oo = bx - 2048;
    const float4 w = ((const float4*)(wo + (size_t)oo * 1024))[t];
    us4 ob; ob.x = f2bf(w.x); ob.y = f2bf(w.y); ob.z = f2bf(w.z); ob.w = f2bf(w.w);
    ((us4*)(wob + (size_t)oo * 1024))[t] = ob;
    const float4 b = ((const float4*)bv)[t];
    float a = w.x * b.x + w.y * b.y + w.z * b.z + w.w * b.w;
    #pragma unroll
    for (int off = 32; off; off >>= 1) a += __shfl_down(a, off, 64);
    if ((t & 63) == 0) lsm[t >> 6] = a;
    __syncthreads();
    if (t == 0) cvec[oo] = lsm[0] + lsm[1] + lsm[2] + lsm[3] + bo[oo];
  } else {
    const int row = bx - 3072;
    const int q = row & 2047, bb = row >> 11;
    const float* pb = pos + ((size_t)bb << 11) * 3;
    const float qx = pb[q*3], qy = pb[q*3+1], qz = pb[q*3+2];
    const float4* pb4 = (const float4*)pb;
    const int jmax = ((q >> 7) + 1) << 7;
    float v[2][4];
    float sum = 0.f;
    #pragma unroll
    for (int cc = 0; cc < 2; cc++) {
      const int j0 = (cc << 10) + (t << 2);
      float e0 = 0.f, e1 = 0.f, e2 = 0.f, e3 = 0.f;
      if (j0 < jmax) {
        const float4 A4 = pb4[3*(j0 >> 2)], B4 = pb4[3*(j0 >> 2) + 1], C4 = pb4[3*(j0 >> 2) + 2];
        const float px[4] = {A4.x, A4.w, B4.z, C4.y};
        const float py[4] = {A4.y, B4.x, B4.w, C4.z};
        const float pz[4] = {A4.z, B4.y, C4.x, C4.w};
        float ee[4];
        #pragma unroll
        for (int u = 0; u < 4; u++) {
          float e = 0.f;
          if (j0 + u <= q) {
            float dx = qx - px[u], dy = qy - py[u], dz = qz - pz[u];
            float sq = fmaf(dx, dx, fmaf(dy, dy, dz*dz));
            float d = sq > 0.f ? sqrtf(sq) : 0.f;
            e = __expf(-0.125f * d);
          }
          ee[u] = e;
        }
        e0 = ee[0]; e1 = ee[1]; e2 = ee[2]; e3 = ee[3];
      }
      v[cc][0] = e0; v[cc][1] = e1; v[cc][2] = e2; v[cc][3] = e3;
      sum += e0 + e1 + e2 + e3;
    }
    #pragma unroll
    for (int off = 32; off; off >>= 1) sum += __shfl_down(sum, off, 64);
    if ((t & 63) == 0) lsm[t >> 6] = sum;
    __syncthreads();
    const float inv = 1.f / (lsm[0] + lsm[1] + lsm[2] + lsm[3]);
    unsigned short* orow = Ab + (size_t)row * 2048;
    #pragma unroll
    for (int cc = 0; cc < 2; cc++) {
      const int j0 = (cc << 10) + (t << 2);
      if (j0 < jmax) {
        us4 o;
        o.x = f2bf(v[cc][0]*inv); o.y = f2bf(v[cc][1]*inv);
        o.z = f2bf(v[cc][2]*inv); o.w = f2bf(v[cc][3]*inv);
        *(us4*)(orow + j0) = o;
      }
    }
  }
}

// ---------- 3-ring loop: BK=64, one barrier/step, counted vmcnt ----------
template<int BM, int BN, int WM, int WN>
__device__ __forceinline__ void gemm_ring(
    const unsigned short* __restrict__ A, int lda,
    const unsigned short* __restrict__ Bt, int ldb,
    int m0, int n0, int kmax,
    unsigned short* lds, f32x4* acc) {
  constexpr int WAVES = WM * WN;
  constexpr int FI = BM / (WM * 16), FJ = BN / (WN * 16);
  constexpr int CPW = ((BM + BN) / 8) / WAVES;
  constexpr int BUFSZ = (BM + BN) * 64;
  const int tid = threadIdx.x, l = tid & 63, w = tid >> 6;
  const int wm = w & (WM - 1), wn = w / WM;
  const int gcol = ((l & 7) ^ (l >> 3)) << 3;      // pre-swizzled k-chunk (elems)

  auto stage = [&](int buf, int k0) {
    unsigned short* base = lds + buf * BUFSZ;
    #pragma unroll
    for (int e = 0; e < CPW; ++e) {
      const int c = w * CPW + e;
      const unsigned short* src;
      unsigned short* dst;
      if (c < BM / 8) {
        src = A + (size_t)(m0 + c*8 + (l >> 3)) * lda + k0 + gcol;
        dst = base + c * 512;
      } else {
        const int cb = c - BM / 8;
        src = Bt + (size_t)(n0 + cb*8 + (l >> 3)) * ldb + k0 + gcol;
        dst = base + BM * 64 + cb * 512;
      }
      __builtin_amdgcn_global_load_lds(AS1(src), AS3(dst), 16, 0, 0);
    }
  };

  auto compute = [&](int buf) {
    unsigned short* lA = lds + buf * BUFSZ;
    unsigned short* lB = lA + BM * 64;
    #pragma unroll
    for (int h = 0; h < 2; ++h) {
      const int slot = ((h << 2) | (l >> 4)) ^ (l & 7);
      bf16x8 af[FI], bfr[FJ];
      #pragma unroll
      for (int i = 0; i < FI; ++i) {
        const int ar = wm * (BM / WM) + i * 16 + (l & 15);
        af[i] = *(const bf16x8*)&lA[ar * 64 + slot * 8];
      }
      #pragma unroll
      for (int j = 0; j < FJ; ++j) {
        const int br = wn * (BN / WN) + j * 16 + (l & 15);
        bfr[j] = *(const bf16x8*)&lB[br * 64 + slot * 8];
      }
      #pragma unroll
      for (int i = 0; i < FI; ++i)
        #pragma unroll
        for (int j = 0; j < FJ; ++j)
          acc[i * FJ + j] = __builtin_amdgcn_mfma_f32_16x16x32_bf16(af[i], bfr[j], acc[i * FJ + j], 0, 0, 0);
    }
  };

  const int NT = kmax >> 6;
  stage(0, 0);
  if (NT > 1) stage(1, 64);
  int cur = 0, nxt2 = 2;
  for (int t = 0; t < NT; ++t) {
    if (t < NT - 1) {
      static_assert(CPW == 4 || CPW == 6 || CPW == 8, "vmcnt literal");
      if constexpr (CPW == 4) asm volatile("s_waitcnt vmcnt(4) lgkmcnt(0)" ::: "memory");
      else if constexpr (CPW == 6) asm volatile("s_waitcnt vmcnt(6) lgkmcnt(0)" ::: "memory");
      else asm volatile("s_waitcnt vmcnt(8) lgkmcnt(0)" ::: "memory");
    } else {
      asm volatile("s_waitcnt vmcnt(0) lgkmcnt(0)" ::: "memory");
    }
    __builtin_amdgcn_s_barrier();
    if (t + 2 < NT) stage(nxt2, (t + 2) << 6);
    compute(cur);
    cur = cur == 2 ? 0 : cur + 1;
    nxt2 = nxt2 == 2 ? 0 : nxt2 + 1;
  }
}

// ---------- fused GEMM chain: tickets 0..511 ax, 512..767 wc, 768..1279 out ----------
// sync[0] = ticket; sync[1+i] (i<32) = ax m-tile counters (b*16+mi);
// sync[33+r] (r<16) = wc col-tile counters. Ticket assignment makes out work
// start only after all producer tickets are held by running blocks -> no deadlock
// regardless of dispatch order (G16-safe). Agent-scope acq/rel as in R8's gridbar.
__global__ __launch_bounds__(256, 2) void k_gemm_all(
    const unsigned short* __restrict__ Ab, const unsigned short* __restrict__ xT,
    unsigned short* __restrict__ Axb,
    const unsigned short* __restrict__ wob, const unsigned short* __restrict__ wvT,
    unsigned short* __restrict__ Wcs, const float* __restrict__ cvec,
    float* __restrict__ out, unsigned* __restrict__ sync) {
  __shared__ __align__(16) unsigned short lds[3 * (128 + 64) * 64];   // 72 KB
  __shared__ unsigned item_s;
  const int tid = threadIdx.x;
  if (tid == 0)
    item_s = __hip_atomic_fetch_add(&sync[0], 1u, __ATOMIC_RELAXED, __HIP_MEMORY_SCOPE_AGENT);
  __syncthreads();
  const int bx = (int)item_s;
  const int l = tid & 63, w = tid >> 6;
  const int wm = w & 1, wn = w >> 1;

  if (bx < 512) {
    // ---- ax: causal A@x, XCD-grouped A-panels + LPT ----
    f32x4 acc[8] = {};
    const int xcd = bx & 7, rest = bx >> 3;
    const int g = rest >> 4, n0i = rest & 15;
    const int mi = (g < 2) ? (15 - xcd) : xcd;
    const int b = g & 1;
    const int m0 = mi << 7, n0 = n0i << 6;
    const unsigned short* A  = Ab + ((size_t)b << 22);
    const unsigned short* Bt = xT + ((size_t)b << 21);
    gemm_ring<128, 64, 2, 2>(A, 2048, Bt, 2048, m0, n0, (mi + 1) << 7, lds, acc);
    unsigned short* Obase = Axb + ((size_t)b << 11) * 1024;
    #pragma unroll
    for (int i = 0; i < 4; i++) {
      const int r0 = m0 + wm*64 + i*16 + ((l >> 4) << 2);
      #pragma unroll
      for (int j = 0; j < 2; j++) {
        const int cidx = n0 + wn*32 + j*16 + (l & 15);
        #pragma unroll
        for (int t = 0; t < 4; t++)
          Obase[(size_t)(r0 + t) * 1024 + cidx] = f2bf(acc[i*2 + j][t]);
      }
    }
    __syncthreads();                 // all stores drained (vmcnt 0) before signal
    if (tid == 0) {
      __threadfence();
      __hip_atomic_fetch_add(&sync[1 + b*16 + mi], 1u, __ATOMIC_RELEASE, __HIP_MEMORY_SCOPE_AGENT);
    }
  } else if (bx < 768) {
    // ---- wc: Wcs = Wo@Wv 64x64 tile ----
    f32x4 acc[4] = {};
    const int g = bx - 512;
    const int m0 = (g & 15) * 64, n0 = (g >> 4) * 64;
    gemm_ring<64, 64, 2, 2>(wob, 1024, wvT, 1024, m0, n0, 1024, lds, acc);
    #pragma unroll
    for (int i = 0; i < 2; i++) {
      const int r0 = m0 + wm*32 + i*16 + ((l >> 4) << 2);
      #pragma unroll
      for (int j = 0; j < 2; j++) {
        const int cidx = n0 + wn*32 + j*16 + (l & 15);
        #pragma unroll
        for (int t = 0; t < 4; t++)
          Wcs[(size_t)(r0 + t) * 1024 + cidx] = f2bf(acc[i*2 + j][t]);
      }
    }
    __syncthreads();
    if (tid == 0) {
      __threadfence();
      __hip_atomic_fetch_add(&sync[33 + (g & 15)], 1u, __ATOMIC_RELEASE, __HIP_MEMORY_SCOPE_AGENT);
    }
  } else {
    // ---- out tile: wait for its 16 ax producers + 16 wc producers ----
    const int u = bx - 768;
    const int m = u & 31, n = u >> 5;          // same m-fast layout as R13 grid(32,16)
    if (tid == 0) {
      while (__hip_atomic_load(&sync[1 + m], __ATOMIC_ACQUIRE, __HIP_MEMORY_SCOPE_AGENT) < 16u)
        __builtin_amdgcn_s_sleep(2);
      while (__hip_atomic_load(&sync[33 + n], __ATOMIC_ACQUIRE, __HIP_MEMORY_SCOPE_AGENT) < 16u)
        __builtin_amdgcn_s_sleep(2);
      __threadfence();
    }
    __syncthreads();
    f32x4 acc[8] = {};
    const int m0 = m * 128, n0 = n * 64;
    gemm_ring<128, 64, 2, 2>(Axb, 1024, Wcs, 1024, m0, n0, 1024, lds, acc);
    #pragma unroll
    for (int i = 0; i < 4; i++) {
      const int r0 = m0 + wm*64 + i*16 + ((l >> 4) << 2);
      #pragma unroll
      for (int j = 0; j < 2; j++) {
        const int cidx = n0 + wn*32 + j*16 + (l & 15);
        const float cv = cvec[cidx];
        #pragma unroll
        for (int t = 0; t < 4; t++)
          out[(size_t)(r0 + t) * 1024 + cidx] = acc[i*2 + j][t] + cv;
      }
    }
  }
}

extern "C" void kernel_launch(void* const* d_in, const int* in_sizes, int n_in,
                              void* d_out, int out_size, void* d_ws, size_t ws_size,
                              hipStream_t stream) {
  const float* x   = (const float*)d_in[0];
  const float* wv  = (const float*)d_in[5];
  const float* bv  = (const float*)d_in[6];
  const float* wo  = (const float*)d_in[7];
  const float* bo  = (const float*)d_in[8];
  const float* w3d = (const float*)d_in[9];
  const float* b3d = (const float*)d_in[10];
  float* out = (float*)d_out;

  char* ws = (char*)d_ws;
  unsigned short* xT  = (unsigned short*)(ws);                //  8 MB [2][1024][2048]
  unsigned short* wvT = (unsigned short*)(ws + ( 8u << 20));  //  2 MB wv^T
  unsigned short* wob = (unsigned short*)(ws + (10u << 20));  //  2 MB
  unsigned short* Wcs = (unsigned short*)(ws + (12u << 20));  //  2 MB (Wo@Wv)[o][i]
  unsigned short* Axb = (unsigned short*)(ws + (14u << 20));  //  8 MB [4096][1024]
  unsigned short* Ab  = (unsigned short*)(ws + (22u << 20));  // 16 MB [2][2048][2048]
  float*          pos = (float*)(ws + (38u << 20));           // 48 KB
  float*          cvec= (float*)(ws + (39u << 20));           //  4 KB
  unsigned*       sync= (unsigned*)(ws + (40u << 20));        // 49 u32

  hipMemsetAsync(sync, 0, 49 * sizeof(unsigned), stream);
  k_pos<<<4096, 256, 0, stream>>>(x, w3d, b3d, pos);
  k_fused<<<7168, 256, 0, stream>>>(x, wv, wo, bv, bo, pos, xT, wvT, wob, cvec, Ab);
  k_gemm_all<<<1280, 256, 0, stream>>>(Ab, xT, Axb, wob, wvT, Wcs, cvec, out, sync);
}

// Round 17
// 56.658 us; speedup vs baseline: 3.6279x; 3.6279x over previous
//
#include <hip/hip_runtime.h>
#include <hip/hip_bf16.h>
#include <stdint.h>

// Pipeline: out = (A @ x) @ Wc + cvec, where Wcs = Wo@Wv (bf16, row-major [o][i]),
// A = causal softmax(-cdist(pos)/8) (head-independent, rows sum to 1),
// cvec = Wo@bv + bo. B=2, S=2048, D=1024.
// R17 = byte-exact revert to R13 (best measured: 56.70 us).

typedef __attribute__((ext_vector_type(8))) short bf16x8;
typedef __attribute__((ext_vector_type(4))) float f32x4;
typedef __attribute__((ext_vector_type(4))) unsigned short us4;

#define AS1(p) (const __attribute__((address_space(1))) unsigned int*)(p)
#define AS3(p) (__attribute__((address_space(3))) unsigned int*)(p)

__device__ __forceinline__ unsigned short f2bf(float f) {
  union { float f; unsigned u; } v; v.f = f;
  unsigned r = v.u + 0x7FFFu + ((v.u >> 16) & 1u);   // RNE
  return (unsigned short)(r >> 16);
}

// ---------- k_prep: 4 block-uniform branches ----------
__global__ void k_prep(const float* __restrict__ x, const float* __restrict__ wv,
                       const float* __restrict__ wo, const float* __restrict__ bv,
                       const float* __restrict__ bo, const float* __restrict__ w3d,
                       const float* __restrict__ b3d,
                       unsigned short* __restrict__ xT, unsigned short* __restrict__ wvT,
                       unsigned short* __restrict__ wob, float* __restrict__ cvec,
                       float* __restrict__ pos) {
  __shared__ __align__(16) float lsm[64 * 68];
  const int bx = blockIdx.x, t = threadIdx.x;
  if (bx < 1024) {
    const int b = bx >> 9, rest = bx & 511, st = rest >> 4, dt = rest & 15;
    const int s0 = st * 64, d0 = dt * 64;
    const int r = t >> 2, c4 = t & 3;
    const float* src = x + (size_t)(b * 2048 + s0 + r) * 1024 + d0;
    float (*ld)[68] = (float(*)[68])lsm;
    #pragma unroll
    for (int p = 0; p < 4; p++)
      *(float4*)&ld[r][(c4 + 4 * p) * 4] = ((const float4*)src)[c4 + 4 * p];
    __syncthreads();
    #pragma unroll
    for (int p = 0; p < 4; p++) {
      const int dl = (t >> 4) + (p << 4);
      us4 o;
      #pragma unroll
      for (int k = 0; k < 4; k++)
        ((unsigned short*)&o)[k] = f2bf(ld[(t & 15) * 4 + k][dl]);
      *(us4*)(xT + ((size_t)b << 21) + (size_t)(d0 + dl) * 2048 + s0 + (t & 15) * 4) = o;
    }
  } else if (bx < 2048) {
    const int bb = bx - 1024, tr = bb >> 5, tc = bb & 31;
    const int r = t >> 5, c = t & 31;
    float (*ld)[33] = (float(*)[33])lsm;
    #pragma unroll
    for (int rr = r; rr < 32; rr += 8)
      ld[rr][c] = wv[(size_t)(tr * 32 + rr) * 1024 + tc * 32 + c];
    __syncthreads();
    #pragma unroll
    for (int rr = r; rr < 32; rr += 8)
      wvT[(size_t)(tc * 32 + rr) * 1024 + tr * 32 + c] = f2bf(ld[c][rr]);
  } else if (bx < 3072) {
    const int oo = bx - 2048;
    const float4 w = ((const float4*)(wo + (size_t)oo * 1024))[t];
    us4 ob; ob.x = f2bf(w.x); ob.y = f2bf(w.y); ob.z = f2bf(w.z); ob.w = f2bf(w.w);
    ((us4*)(wob + (size_t)oo * 1024))[t] = ob;
    const float4 b = ((const float4*)bv)[t];
    float a = w.x * b.x + w.y * b.y + w.z * b.z + w.w * b.w;
    #pragma unroll
    for (int off = 32; off; off >>= 1) a += __shfl_down(a, off, 64);
    if ((t & 63) == 0) lsm[t >> 6] = a;
    __syncthreads();
    if (t == 0) cvec[oo] = lsm[0] + lsm[1] + lsm[2] + lsm[3] + bo[oo];
  } else {
    const int row = bx - 3072;
    const float4 xv = ((const float4*)(x + (size_t)row * 1024))[t];
    const float4 w0 = ((const float4*)(w3d))[t];
    const float4 w1 = ((const float4*)(w3d + 1024))[t];
    const float4 w2 = ((const float4*)(w3d + 2048))[t];
    float a0 = xv.x*w0.x + xv.y*w0.y + xv.z*w0.z + xv.w*w0.w;
    float a1 = xv.x*w1.x + xv.y*w1.y + xv.z*w1.z + xv.w*w1.w;
    float a2 = xv.x*w2.x + xv.y*w2.y + xv.z*w2.z + xv.w*w2.w;
    #pragma unroll
    for (int off = 32; off; off >>= 1) {
      a0 += __shfl_down(a0, off, 64);
      a1 += __shfl_down(a1, off, 64);
      a2 += __shfl_down(a2, off, 64);
    }
    if ((t & 63) == 0) { lsm[(t >> 6) * 3] = a0; lsm[(t >> 6) * 3 + 1] = a1; lsm[(t >> 6) * 3 + 2] = a2; }
    __syncthreads();
    if (t == 0) {
      pos[(size_t)row*3 + 0] = lsm[0] + lsm[3] + lsm[6] + lsm[9]  + b3d[0];
      pos[(size_t)row*3 + 1] = lsm[1] + lsm[4] + lsm[7] + lsm[10] + b3d[1];
      pos[(size_t)row*3 + 2] = lsm[2] + lsm[5] + lsm[8] + lsm[11] + b3d[2];
    }
  }
}

// ---------- k_attn: causal-truncated (row q only needs j < jmax = tile-end) ----------
__global__ void k_attn(const float* __restrict__ pos, unsigned short* __restrict__ Ab) {
  const int row = blockIdx.x;
  const int q = row & 2047, bb = row >> 11;
  const float* pb = pos + ((size_t)bb << 11) * 3;
  const float qx = pb[q*3], qy = pb[q*3+1], qz = pb[q*3+2];
  const float4* pb4 = (const float4*)pb;
  const int jmax = ((q >> 7) + 1) << 7;          // ax only reads j < jmax
  float v[2][4];
  float sum = 0.f;
  #pragma unroll
  for (int cc = 0; cc < 2; cc++) {
    const int j0 = (cc << 10) + (threadIdx.x << 2);
    float e0 = 0.f, e1 = 0.f, e2 = 0.f, e3 = 0.f;
    if (j0 < jmax) {
      const float4 A4 = pb4[3*(j0 >> 2)], B4 = pb4[3*(j0 >> 2) + 1], C4 = pb4[3*(j0 >> 2) + 2];
      const float px[4] = {A4.x, A4.w, B4.z, C4.y};
      const float py[4] = {A4.y, B4.x, B4.w, C4.z};
      const float pz[4] = {A4.z, B4.y, C4.x, C4.w};
      float ee[4];
      #pragma unroll
      for (int u = 0; u < 4; u++) {
        float e = 0.f;
        if (j0 + u <= q) {
          float dx = qx - px[u], dy = qy - py[u], dz = qz - pz[u];
          float sq = fmaf(dx, dx, fmaf(dy, dy, dz*dz));
          float d = sq > 0.f ? sqrtf(sq) : 0.f;
          e = __expf(-0.125f * d);
        }
        ee[u] = e;
      }
      e0 = ee[0]; e1 = ee[1]; e2 = ee[2]; e3 = ee[3];
    }
    v[cc][0] = e0; v[cc][1] = e1; v[cc][2] = e2; v[cc][3] = e3;
    sum += e0 + e1 + e2 + e3;
  }
  #pragma unroll
  for (int off = 32; off; off >>= 1) sum += __shfl_down(sum, off, 64);
  __shared__ float red[4];
  if ((threadIdx.x & 63) == 0) red[threadIdx.x >> 6] = sum;
  __syncthreads();
  const float inv = 1.f / (red[0] + red[1] + red[2] + red[3]);
  unsigned short* orow = Ab + (size_t)row * 2048;
  #pragma unroll
  for (int cc = 0; cc < 2; cc++) {
    const int j0 = (cc << 10) + (threadIdx.x << 2);
    if (j0 < jmax) {
      us4 o;
      o.x = f2bf(v[cc][0]*inv); o.y = f2bf(v[cc][1]*inv);
      o.z = f2bf(v[cc][2]*inv); o.w = f2bf(v[cc][3]*inv);
      *(us4*)(orow + j0) = o;
    }
  }
}

// ---------- 3-ring loop: BK=64, one barrier/step, counted vmcnt ----------
template<int BM, int BN, int WM, int WN>
__device__ __forceinline__ void gemm_ring(
    const unsigned short* __restrict__ A, int lda,
    const unsigned short* __restrict__ Bt, int ldb,
    int m0, int n0, int kmax,
    unsigned short* lds, f32x4* acc) {
  constexpr int WAVES = WM * WN;
  constexpr int FI = BM / (WM * 16), FJ = BN / (WN * 16);
  constexpr int CPW = ((BM + BN) / 8) / WAVES;
  constexpr int BUFSZ = (BM + BN) * 64;
  const int tid = threadIdx.x, l = tid & 63, w = tid >> 6;
  const int wm = w & (WM - 1), wn = w / WM;
  const int gcol = ((l & 7) ^ (l >> 3)) << 3;      // pre-swizzled k-chunk (elems)

  auto stage = [&](int buf, int k0) {
    unsigned short* base = lds + buf * BUFSZ;
    #pragma unroll
    for (int e = 0; e < CPW; ++e) {
      const int c = w * CPW + e;
      const unsigned short* src;
      unsigned short* dst;
      if (c < BM / 8) {
        src = A + (size_t)(m0 + c*8 + (l >> 3)) * lda + k0 + gcol;
        dst = base + c * 512;
      } else {
        const int cb = c - BM / 8;
        src = Bt + (size_t)(n0 + cb*8 + (l >> 3)) * ldb + k0 + gcol;
        dst = base + BM * 64 + cb * 512;
      }
      __builtin_amdgcn_global_load_lds(AS1(src), AS3(dst), 16, 0, 0);
    }
  };

  auto compute = [&](int buf) {
    unsigned short* lA = lds + buf * BUFSZ;
    unsigned short* lB = lA + BM * 64;
    #pragma unroll
    for (int h = 0; h < 2; ++h) {
      const int slot = ((h << 2) | (l >> 4)) ^ (l & 7);
      bf16x8 af[FI], bfr[FJ];
      #pragma unroll
      for (int i = 0; i < FI; ++i) {
        const int ar = wm * (BM / WM) + i * 16 + (l & 15);
        af[i] = *(const bf16x8*)&lA[ar * 64 + slot * 8];
      }
      #pragma unroll
      for (int j = 0; j < FJ; ++j) {
        const int br = wn * (BN / WN) + j * 16 + (l & 15);
        bfr[j] = *(const bf16x8*)&lB[br * 64 + slot * 8];
      }
      #pragma unroll
      for (int i = 0; i < FI; ++i)
        #pragma unroll
        for (int j = 0; j < FJ; ++j)
          acc[i * FJ + j] = __builtin_amdgcn_mfma_f32_16x16x32_bf16(af[i], bfr[j], acc[i * FJ + j], 0, 0, 0);
    }
  };

  const int NT = kmax >> 6;
  stage(0, 0);
  if (NT > 1) stage(1, 64);
  int cur = 0, nxt2 = 2;
  for (int t = 0; t < NT; ++t) {
    if (t < NT - 1) {
      static_assert(CPW == 4 || CPW == 6 || CPW == 8, "vmcnt literal");
      if constexpr (CPW == 4) asm volatile("s_waitcnt vmcnt(4) lgkmcnt(0)" ::: "memory");
      else if constexpr (CPW == 6) asm volatile("s_waitcnt vmcnt(6) lgkmcnt(0)" ::: "memory");
      else asm volatile("s_waitcnt vmcnt(8) lgkmcnt(0)" ::: "memory");
    } else {
      asm volatile("s_waitcnt vmcnt(0) lgkmcnt(0)" ::: "memory");
    }
    __builtin_amdgcn_s_barrier();
    if (t + 2 < NT) stage(nxt2, (t + 2) << 6);
    compute(cur);
    cur = cur == 2 ? 0 : cur + 1;
    nxt2 = nxt2 == 2 ? 0 : nxt2 + 1;
  }
}

// ---------- fused GEMM: [0,512) causal ax, XCD-grouped A-panels + LPT; [512,768) wc ----------
__global__ __launch_bounds__(256, 2) void k_gemm_axwc(
    const unsigned short* __restrict__ Ab, const unsigned short* __restrict__ xT,
    unsigned short* __restrict__ Axb,
    const unsigned short* __restrict__ wob, const unsigned short* __restrict__ wvT,
    unsigned short* __restrict__ Wcs) {
  __shared__ __align__(16) unsigned short lds[3 * (128 + 64) * 64];   // 72 KB
  const int bx = blockIdx.x;
  const int l = threadIdx.x & 63, w = threadIdx.x >> 6;
  const int wm = w & 1, wn = w >> 1;
  if (bx < 512) {
    f32x4 acc[8] = {};
    const int xcd = bx & 7, rest = bx >> 3;       // rest 0..63
    const int g = rest >> 4, n0i = rest & 15;     // g 0..3: LPT (long mi first)
    const int mi = (g < 2) ? (15 - xcd) : xcd;
    const int b = g & 1;
    const int m0 = mi << 7, n0 = n0i << 6;
    const unsigned short* A  = Ab + ((size_t)b << 22);
    const unsigned short* Bt = xT + ((size_t)b << 21);
    gemm_ring<128, 64, 2, 2>(A, 2048, Bt, 2048, m0, n0, (mi + 1) << 7, lds, acc);
    unsigned short* Obase = Axb + ((size_t)b << 11) * 1024;
    #pragma unroll
    for (int i = 0; i < 4; i++) {
      const int r0 = m0 + wm*64 + i*16 + ((l >> 4) << 2);
      #pragma unroll
      for (int j = 0; j < 2; j++) {
        const int cidx = n0 + wn*32 + j*16 + (l & 15);
        #pragma unroll
        for (int t = 0; t < 4; t++)
          Obase[(size_t)(r0 + t) * 1024 + cidx] = f2bf(acc[i*2 + j][t]);
      }
    }
  } else {
    f32x4 acc[4] = {};
    const int g = bx - 512;
    const int m0 = (g & 15) * 64, n0 = (g >> 4) * 64;
    gemm_ring<64, 64, 2, 2>(wob, 1024, wvT, 1024, m0, n0, 1024, lds, acc);
    #pragma unroll
    for (int i = 0; i < 2; i++) {
      const int r0 = m0 + wm*32 + i*16 + ((l >> 4) << 2);
      #pragma unroll
      for (int j = 0; j < 2; j++) {
        const int cidx = n0 + wn*32 + j*16 + (l & 15);
        #pragma unroll
        for (int t = 0; t < 4; t++)
          Wcs[(size_t)(r0 + t) * 1024 + cidx] = f2bf(acc[i*2 + j][t]);
      }
    }
  }
}

// ---------- out[r][o] = sum_d Axb[r][d] Wcs[o][d] + cvec[o] (fp32), 128x64 ring ----------
// grid (32 m, 16 n): same-m blocks stride 32 in bid -> bid%8 = m%8 -> A-panel co-XCD.
__global__ __launch_bounds__(256, 2) void k_gemm_out(
    const unsigned short* __restrict__ Axb, const unsigned short* __restrict__ Wcs,
    const float* __restrict__ cvec, float* __restrict__ out) {
  __shared__ __align__(16) unsigned short lds[3 * (128 + 64) * 64];   // 72 KB
  f32x4 acc[8] = {};
  const int m0 = blockIdx.x * 128, n0 = blockIdx.y * 64;
  gemm_ring<128, 64, 2, 2>(Axb, 1024, Wcs, 1024, m0, n0, 1024, lds, acc);
  const int l = threadIdx.x & 63, w = threadIdx.x >> 6;
  const int wm = w & 1, wn = w >> 1;
  #pragma unroll
  for (int i = 0; i < 4; i++) {
    const int r0 = m0 + wm*64 + i*16 + ((l >> 4) << 2);
    #pragma unroll
    for (int j = 0; j < 2; j++) {
      const int cidx = n0 + wn*32 + j*16 + (l & 15);
      const float cv = cvec[cidx];
      #pragma unroll
      for (int t = 0; t < 4; t++)
        out[(size_t)(r0 + t) * 1024 + cidx] = acc[i*2 + j][t] + cv;
    }
  }
}

extern "C" void kernel_launch(void* const* d_in, const int* in_sizes, int n_in,
                              void* d_out, int out_size, void* d_ws, size_t ws_size,
                              hipStream_t stream) {
  const float* x   = (const float*)d_in[0];
  const float* wv  = (const float*)d_in[5];
  const float* bv  = (const float*)d_in[6];
  const float* wo  = (const float*)d_in[7];
  const float* bo  = (const float*)d_in[8];
  const float* w3d = (const float*)d_in[9];
  const float* b3d = (const float*)d_in[10];
  float* out = (float*)d_out;

  char* ws = (char*)d_ws;
  unsigned short* xT  = (unsigned short*)(ws);                //  8 MB [2][1024][2048]
  unsigned short* wvT = (unsigned short*)(ws + ( 8u << 20));  //  2 MB wv^T
  unsigned short* wob = (unsigned short*)(ws + (10u << 20));  //  2 MB
  unsigned short* Wcs = (unsigned short*)(ws + (12u << 20));  //  2 MB (Wo@Wv)[o][i]
  unsigned short* Axb = (unsigned short*)(ws + (14u << 20));  //  8 MB [4096][1024]
  unsigned short* Ab  = (unsigned short*)(ws + (22u << 20));  // 16 MB [2][2048][2048]
  float*          pos = (float*)(ws + (38u << 20));           // 48 KB
  float*          cvec= (float*)(ws + (39u << 20));           //  4 KB

  k_prep<<<7168, 256, 0, stream>>>(x, wv, wo, bv, bo, w3d, b3d, xT, wvT, wob, cvec, pos);
  k_attn<<<4096, 256, 0, stream>>>(pos, Ab);
  k_gemm_axwc<<<768, 256, 0, stream>>>(Ab, xT, Axb, wob, wvT, Wcs);
  k_gemm_out<<<dim3(32, 16), 256, 0, stream>>>(Axb, Wcs, cvec, out);
}